// Round 2
// baseline (2396.942 us; speedup 1.0000x reference)
//
#include <hip/hip_runtime.h>
#include <math.h>

#define N_NODES 50000
#define N_RELS  500
#define N_EDGE  800000
#define HID     64
#define HEADS   4
#define DH      16
#define LAYERS  2
#define HOPS    3
#define TOPK    10
#define ALPHA   0.15f
#define SLOPE   0.2f

#define SCAN_NBLK 13   // ceil(50000/4096)

typedef unsigned long long u64;

// ---------------------------------------------------------------- CSR build
__global__ void hist_kernel(const int* __restrict__ dst, int* __restrict__ counts) {
    int t = blockIdx.x * 256 + threadIdx.x;
    if (t < N_EDGE) atomicAdd(&counts[dst[t]], 1);
}

// block partial sums: 13 blocks x 1024 threads x 4 elems
__global__ void scan_partial(const int* __restrict__ counts, int* __restrict__ blk_sum) {
    int t = threadIdx.x, b = blockIdx.x;
    int i0 = b * 4096 + t * 4;
    int s = 0;
    #pragma unroll
    for (int q = 0; q < 4; ++q) { int i = i0 + q; if (i < N_NODES) s += counts[i]; }
    #pragma unroll
    for (int off = 32; off > 0; off >>= 1) s += __shfl_down(s, off, 64);
    __shared__ int ws[16];
    if ((t & 63) == 0) ws[t >> 6] = s;
    __syncthreads();
    if (t == 0) { int tot = 0; for (int i = 0; i < 16; ++i) tot += ws[i]; blk_sum[b] = tot; }
}

__global__ void scan_small(int* __restrict__ blk_sum, int* __restrict__ row_ptr) {
    if (threadIdx.x == 0) {
        int acc = 0;
        for (int i = 0; i < SCAN_NBLK; ++i) { int v = blk_sum[i]; blk_sum[i] = acc; acc += v; }
        row_ptr[N_NODES] = acc;   // == N_EDGE
    }
}

__global__ void scan_final(const int* __restrict__ counts, const int* __restrict__ blk_sum,
                           int* __restrict__ row_ptr) {
    __shared__ int wtot[16];
    __shared__ int wpre[16];
    int b = blockIdx.x, t = threadIdx.x;
    int lane = t & 63, wid = t >> 6;
    int i0 = b * 4096 + t * 4;
    int x0 = (i0 + 0 < N_NODES) ? counts[i0 + 0] : 0;
    int x1 = (i0 + 1 < N_NODES) ? counts[i0 + 1] : 0;
    int x2 = (i0 + 2 < N_NODES) ? counts[i0 + 2] : 0;
    int x3 = (i0 + 3 < N_NODES) ? counts[i0 + 3] : 0;
    int tsum = x0 + x1 + x2 + x3;
    int v = tsum;
    #pragma unroll
    for (int off = 1; off < 64; off <<= 1) {
        int u = __shfl_up(v, off, 64);
        if (lane >= off) v += u;
    }
    if (lane == 63) wtot[wid] = v;
    __syncthreads();
    if (wid == 0) {
        int wv = (lane < 16) ? wtot[lane] : 0;
        #pragma unroll
        for (int off = 1; off < 16; off <<= 1) {
            int u = __shfl_up(wv, off, 64);
            if (lane >= off) wv += u;
        }
        if (lane < 16) wpre[lane] = wv;
    }
    __syncthreads();
    int wbase = (wid == 0) ? 0 : wpre[wid - 1];
    int ex = blk_sum[b] + wbase + (v - tsum);
    if (i0 + 0 < N_NODES) row_ptr[i0 + 0] = ex;
    if (i0 + 1 < N_NODES) row_ptr[i0 + 1] = ex + x0;
    if (i0 + 2 < N_NODES) row_ptr[i0 + 2] = ex + x0 + x1;
    if (i0 + 3 < N_NODES) row_ptr[i0 + 3] = ex + x0 + x1 + x2;
}

// one packed 8B scatter per edge: [eid:32 | rel:16 | src:16]
__global__ void scatter_kernel(const int* __restrict__ src, const int* __restrict__ dst,
                               const int* __restrict__ rel, const int* __restrict__ row_ptr,
                               int* __restrict__ cursor, u64* __restrict__ sorted_pack) {
    int t = blockIdx.x * 256 + threadIdx.x;
    if (t >= N_EDGE) return;
    int d = dst[t];
    int pos = row_ptr[d] + atomicAdd(&cursor[d], 1);
    sorted_pack[pos] = ((u64)(unsigned)t << 32) | ((unsigned)rel[t] << 16) | (unsigned)src[t];
}

// ---------------------------------------------------------------- dense pieces
// C1 = A@W1 (feat0), C2 = A@W2 (res), plus s_src/s_dst epilogue from C1 tile
__global__ void gemm_dual(const float* __restrict__ A, const float* __restrict__ W1,
                          const float* __restrict__ W2, const float* __restrict__ a_vec,
                          float* __restrict__ C1, float* __restrict__ C2,
                          float* __restrict__ s_src, float* __restrict__ s_dst, int n) {
    __shared__ float W1s[64][64];
    __shared__ float W2s[64][64];
    __shared__ float As[32][65];     // padded: epilogue reads columns
    __shared__ float a_sh[128];
    int t = threadIdx.x;      // 256
    for (int i = t; i < 64 * 64; i += 256) { W1s[i >> 6][i & 63] = W1[i]; W2s[i >> 6][i & 63] = W2[i]; }
    if (t < 128) a_sh[t] = a_vec[t];   // a[0][h][d] then a[1][h][d]
    int row0 = blockIdx.x * 32;
    for (int i = t; i < 32 * 64; i += 256) {
        int r = i >> 6, c = i & 63;
        int gr = row0 + r;
        As[r][c] = (gr < n) ? A[(size_t)gr * 64 + c] : 0.f;
    }
    __syncthreads();
    int col = t & 63;
    int r0 = t >> 6;          // 0..3
    float acc1v[8];
    #pragma unroll
    for (int rr = 0; rr < 8; ++rr) {
        int r = r0 + rr * 4;
        float a1 = 0.f, a2 = 0.f;
        #pragma unroll
        for (int k = 0; k < 64; ++k) {
            float av = As[r][k];
            a1 += av * W1s[k][col];
            a2 += av * W2s[k][col];
        }
        acc1v[rr] = a1;
        int gr = row0 + r;
        if (gr < n) C2[(size_t)gr * 64 + col] = a2;
    }
    __syncthreads();
    #pragma unroll
    for (int rr = 0; rr < 8; ++rr) {
        int r = r0 + rr * 4;
        As[r][col] = acc1v[rr];
        int gr = row0 + r;
        if (gr < n) C1[(size_t)gr * 64 + col] = acc1v[rr];
    }
    __syncthreads();
    if (t < 128) {
        int nl = t >> 2, h = t & 3;
        int gr = row0 + nl;
        if (gr < n) {
            float ss = 0.f, sd = 0.f;
            #pragma unroll
            for (int d = 0; d < 16; ++d) {
                float v = As[nl][h * 16 + d];
                ss += v * a_sh[h * 16 + d];
                sd += v * a_sh[64 + h * 16 + d];
            }
            s_src[gr * 4 + h] = ss;
            s_dst[gr * 4 + h] = sd;
        }
    }
}

// s_rel[r,h] = dot((rel_emb @ W_rel)[r, h*16:...], a2[h,:])
__global__ void rel_scores(const float* __restrict__ rel_emb, const float* __restrict__ Wr,
                           const float* __restrict__ a2, float* __restrict__ s_rel) {
    __shared__ float proj[64];
    int r = blockIdx.x, c = threadIdx.x;   // 64 threads
    float acc = 0.f;
    #pragma unroll
    for (int k = 0; k < 64; ++k) acc += rel_emb[(size_t)r * 64 + k] * Wr[k * 64 + c];
    proj[c] = acc;
    __syncthreads();
    if (c < HEADS) {
        float s = 0.f;
        #pragma unroll
        for (int d = 0; d < 16; ++d) s += proj[c * 16 + d] * a2[c * 16 + d];
        s_rel[r * HEADS + c] = s;
    }
}

// ---------------------------------------------------------------- edge scores (edge-parallel)
__global__ void edge_scores(const u64* __restrict__ pack, const float* __restrict__ s_src,
                            const float* __restrict__ s_rel, float4* __restrict__ sc) {
    int j = blockIdx.x * 256 + threadIdx.x;
    if (j >= N_EDGE) return;
    u64 p = pack[j];
    int src = (int)(p & 0xFFFF);
    int rel = (int)((p >> 16) & 0xFFFF);
    float4 a = *(const float4*)(s_src + (size_t)src * 4);
    float4 b = *(const float4*)(s_rel + (size_t)rel * 4);
    sc[j] = make_float4(a.x + b.x, a.y + b.y, a.z + b.z, a.w + b.w);
}

// ---------------------------------------------------------------- top-k + softmax (streaming)
__global__ void topk_kernel(const int* __restrict__ row_ptr, const u64* __restrict__ pack,
                            const float* __restrict__ sc, const float* __restrict__ s_dst,
                            int* __restrict__ kept_src, float* __restrict__ kept_w,
                            int* __restrict__ kept_cnt) {
    int t = blockIdx.x * 256 + threadIdx.x;
    if (t >= N_NODES * HEADS) return;
    int d = t >> 2, h = t & 3;
    int beg = row_ptr[d], end = row_ptr[d + 1];
    float sdst = s_dst[t];

    float topS[TOPK]; int topI[TOPK]; int topN[TOPK];
    #pragma unroll
    for (int i = 0; i < TOPK; ++i) { topS[i] = -3.4e38f; topI[i] = 0x7fffffff; topN[i] = 0; }

    for (int j = beg; j < end; ++j) {
        float s = sc[(size_t)j * 4 + h] + sdst;
        s = s > 0.f ? s : SLOPE * s;          // leaky relu
        if (s < topS[TOPK - 1]) continue;     // early-out vs current slot 9
        u64 p = pack[j];
        int id = (int)(p >> 32);
        int sn = (int)(p & 0xFFFF);
        if (s == topS[TOPK - 1] && id > topI[TOPK - 1]) continue;
        #pragma unroll
        for (int i = 0; i < TOPK; ++i) {      // rank by (score desc, edge id asc)
            bool better = (s > topS[i]) || (s == topS[i] && id < topI[i]);
            if (better) {
                float ts = topS[i]; int ti = topI[i]; int tn = topN[i];
                topS[i] = s; topI[i] = id; topN[i] = tn == tn ? tn : tn;  // placeholder avoided below
                topN[i] = sn;
                s = ts; id = ti; sn = tn;
            }
        }
    }
    int deg = end - beg;
    int cnt = deg < TOPK ? deg : TOPK;
    float m = (cnt > 0) ? topS[0] : 0.f;
    float w[TOPK]; float den = 0.f;
    #pragma unroll
    for (int i = 0; i < TOPK; ++i) {
        float e = (i < cnt) ? expf(topS[i] - m) : 0.f;
        w[i] = e; den += e;
    }
    float inv = 1.f / (den + 1e-16f);
    #pragma unroll
    for (int i = 0; i < TOPK; ++i) {
        kept_w[(size_t)t * TOPK + i]   = (i < cnt) ? w[i] * inv : 0.f;
        kept_src[(size_t)t * TOPK + i] = topN[i];
    }
    kept_cnt[t] = cnt;
}

// ---------------------------------------------------------------- diffusion hop (float4)
// 256 threads = 16 nodes x 16 float4-lanes
template<bool FINAL>
__global__ void hop_kernel(const float4* __restrict__ hc_in, const float4* __restrict__ feat0,
                           const int* __restrict__ kept_src, const float* __restrict__ kept_w,
                           const int* __restrict__ kept_cnt,
                           const float4* __restrict__ res, float4* __restrict__ out) {
    __shared__ int   ls[16 * HEADS * TOPK];
    __shared__ float lw[16 * HEADS * TOPK];
    __shared__ int   lc[16 * HEADS];
    int tb = threadIdx.x;            // 256
    int nb = blockIdx.x * 16;        // first node
    for (int i = tb; i < 16 * HEADS * TOPK; i += 256) {
        int idx = nb * HEADS * TOPK + i;
        ls[i] = kept_src[idx];
        lw[i] = kept_w[idx];
    }
    if (tb < 16 * HEADS) lc[tb] = kept_cnt[nb * HEADS + tb];
    __syncthreads();
    int nl = tb >> 4;                // node in block
    int c4 = tb & 15;                // float4 column
    int h  = c4 >> 2;
    int lbase = nl * HEADS * TOPK + h * TOPK;
    int cnt = lc[nl * HEADS + h];
    float4 acc = make_float4(0.f, 0.f, 0.f, 0.f);
    for (int k = 0; k < cnt; ++k) {
        float w = lw[lbase + k];
        int s = ls[lbase + k];
        float4 v = hc_in[(size_t)s * 16 + c4];
        acc.x += w * v.x; acc.y += w * v.y; acc.z += w * v.z; acc.w += w * v.w;
    }
    size_t o = (size_t)nb * 16 + tb;
    float4 f = feat0[o];
    float4 r;
    r.x = (1.f - ALPHA) * acc.x + ALPHA * f.x;
    r.y = (1.f - ALPHA) * acc.y + ALPHA * f.y;
    r.z = (1.f - ALPHA) * acc.z + ALPHA * f.z;
    r.w = (1.f - ALPHA) * acc.w + ALPHA * f.w;
    if (FINAL) {
        float4 rs = res[o];
        float x;
        x = r.x + rs.x; r.x = x > 0.f ? x : (expf(x) - 1.f);
        x = r.y + rs.y; r.y = x > 0.f ? x : (expf(x) - 1.f);
        x = r.z + rs.z; r.z = x > 0.f ? x : (expf(x) - 1.f);
        x = r.w + rs.w; r.w = x > 0.f ? x : (expf(x) - 1.f);
    }
    out[o] = r;
}

// ---------------------------------------------------------------- rel output
__global__ void relout_kernel(const float* __restrict__ rel_emb, const float* __restrict__ Wf,
                              float* __restrict__ out) {
    int r = blockIdx.x, c = threadIdx.x;  // 500 x 64
    float acc = 0.f;
    #pragma unroll
    for (int k = 0; k < 64; ++k) acc += rel_emb[(size_t)r * 64 + k] * Wf[k * 64 + c];
    out[(size_t)r * 64 + c] = acc;
}

// ---------------------------------------------------------------- launch
extern "C" void kernel_launch(void* const* d_in, const int* in_sizes, int n_in,
                              void* d_out, int out_size, void* d_ws, size_t ws_size,
                              hipStream_t stream) {
    (void)in_sizes; (void)n_in; (void)out_size; (void)ws_size;
    const float* ent_emb  = (const float*)d_in[0];
    const float* rel_emb  = (const float*)d_in[1];
    const int*   edge_src = (const int*)d_in[2];
    const int*   edge_dst = (const int*)d_in[3];
    const int*   edge_rel = (const int*)d_in[4];
    const float* W_ent    = (const float*)d_in[5];
    const float* W_rel    = (const float*)d_in[6];
    const float* attn_a   = (const float*)d_in[7];
    const float* res_W    = (const float*)d_in[8];
    const float* fc_rel_w = (const float*)d_in[9];

    char* wp = (char*)d_ws;
    auto alloc = [&](size_t bytes) -> void* {
        void* p = (void*)wp;
        wp += (bytes + 255) & ~(size_t)255;
        return p;
    };
    int*   counts     = (int*)alloc((size_t)N_NODES * 4);
    int*   cursor     = (int*)alloc((size_t)N_NODES * 4);
    int*   row_ptr    = (int*)alloc((size_t)(N_NODES + 1) * 4);
    int*   blk_sum    = (int*)alloc((size_t)SCAN_NBLK * 4);
    u64*   sorted_pack= (u64*)alloc((size_t)N_EDGE * 8);
    float* s_src      = (float*)alloc((size_t)N_NODES * HEADS * 4);
    float* s_dst      = (float*)alloc((size_t)N_NODES * HEADS * 4);
    float* s_rel      = (float*)alloc((size_t)N_RELS * HEADS * 4);
    float* feat0      = (float*)alloc((size_t)N_NODES * HID * 4);
    float* hcA        = (float*)alloc((size_t)N_NODES * HID * 4);
    float* hcB        = (float*)alloc((size_t)N_NODES * HID * 4);   // aliased as sc_sorted
    float* res        = (float*)alloc((size_t)N_NODES * HID * 4);
    int*   kept_src   = (int*)alloc((size_t)N_NODES * HEADS * TOPK * 4);
    float* kept_w     = (float*)alloc((size_t)N_NODES * HEADS * TOPK * 4);
    int*   kept_cnt   = (int*)alloc((size_t)N_NODES * HEADS * 4);
    float4* sc_sorted = (float4*)hcB;   // E*16B == N*HID*4B == 12.8 MB, disjoint lifetime

    // ---- CSR by destination (edges are layer-invariant: build once) ----
    hipMemsetAsync(counts, 0, (size_t)N_NODES * 4, stream);
    hipMemsetAsync(cursor, 0, (size_t)N_NODES * 4, stream);
    hist_kernel<<<N_EDGE / 256, 256, 0, stream>>>(edge_dst, counts);
    scan_partial<<<SCAN_NBLK, 1024, 0, stream>>>(counts, blk_sum);
    scan_small<<<1, 64, 0, stream>>>(blk_sum, row_ptr);
    scan_final<<<SCAN_NBLK, 1024, 0, stream>>>(counts, blk_sum, row_ptr);
    scatter_kernel<<<N_EDGE / 256, 256, 0, stream>>>(edge_src, edge_dst, edge_rel, row_ptr,
                                                     cursor, sorted_pack);

    float* out_h = (float*)d_out;     // node rows; layer-1 output also lives here
    const float* h = ent_emb;
    const int nb_gemm = (N_NODES + 31) / 32;
    const int nb_nh   = (N_NODES * HEADS + 255) / 256;
    const int nb_edge = (N_EDGE + 255) / 256;
    const int nb_hop  = N_NODES / 16;   // 3125, exact

    for (int l = 0; l < LAYERS; ++l) {
        const float* We = W_ent + (size_t)l * HID * HID;
        const float* Wr = W_rel + (size_t)l * HID * HID;
        const float* a  = attn_a + (size_t)l * 3 * HEADS * DH;
        const float* rW = res_W + (size_t)l * HID * HID;

        gemm_dual<<<nb_gemm, 256, 0, stream>>>(h, We, rW, a, feat0, res, s_src, s_dst, N_NODES);
        rel_scores<<<N_RELS, 64, 0, stream>>>(rel_emb, Wr, a + 2 * HEADS * DH, s_rel);
        edge_scores<<<nb_edge, 256, 0, stream>>>(sorted_pack, s_src, s_rel, sc_sorted);
        topk_kernel<<<nb_nh, 256, 0, stream>>>(row_ptr, sorted_pack, (const float*)sc_sorted,
                                               s_dst, kept_src, kept_w, kept_cnt);
        hop_kernel<false><<<nb_hop, 256, 0, stream>>>((const float4*)feat0, (const float4*)feat0,
                                                      kept_src, kept_w, kept_cnt, nullptr, (float4*)hcA);
        hop_kernel<false><<<nb_hop, 256, 0, stream>>>((const float4*)hcA, (const float4*)feat0,
                                                      kept_src, kept_w, kept_cnt, nullptr, (float4*)hcB);
        hop_kernel<true><<<nb_hop, 256, 0, stream>>>((const float4*)hcB, (const float4*)feat0,
                                                     kept_src, kept_w, kept_cnt, (const float4*)res,
                                                     (float4*)out_h);
        h = out_h;
    }
    relout_kernel<<<N_RELS, 64, 0, stream>>>(rel_emb, fc_rel_w, (float*)d_out + (size_t)N_NODES * HID);
}

// Round 3
// 502.553 us; speedup vs baseline: 4.7695x; 4.7695x over previous
//
#include <hip/hip_runtime.h>
#include <math.h>

#define N_NODES 50000
#define N_RELS  500
#define N_EDGE  800000
#define HID     64
#define HEADS   4
#define DH      16
#define LAYERS  2
#define HOPS    3
#define TOPK    10
#define ALPHA   0.15f
#define SLOPE   0.2f

#define SCAN_NBLK 13   // ceil(50000/4096)

typedef unsigned long long u64;

// ---------------------------------------------------------------- CSR build
__global__ void hist_kernel(const int* __restrict__ dst, int* __restrict__ counts) {
    int t = blockIdx.x * 256 + threadIdx.x;
    if (t < N_EDGE) atomicAdd(&counts[dst[t]], 1);
}

// block partial sums: 13 blocks x 1024 threads x 4 elems
__global__ void scan_partial(const int* __restrict__ counts, int* __restrict__ blk_sum) {
    int t = threadIdx.x, b = blockIdx.x;
    int i0 = b * 4096 + t * 4;
    int s = 0;
    #pragma unroll
    for (int q = 0; q < 4; ++q) { int i = i0 + q; if (i < N_NODES) s += counts[i]; }
    #pragma unroll
    for (int off = 32; off > 0; off >>= 1) s += __shfl_down(s, off, 64);
    __shared__ int ws[16];
    if ((t & 63) == 0) ws[t >> 6] = s;
    __syncthreads();
    if (t == 0) { int tot = 0; for (int i = 0; i < 16; ++i) tot += ws[i]; blk_sum[b] = tot; }
}

__global__ void scan_small(int* __restrict__ blk_sum, int* __restrict__ row_ptr) {
    if (threadIdx.x == 0) {
        int acc = 0;
        for (int i = 0; i < SCAN_NBLK; ++i) { int v = blk_sum[i]; blk_sum[i] = acc; acc += v; }
        row_ptr[N_NODES] = acc;   // == N_EDGE
    }
}

__global__ void scan_final(const int* __restrict__ counts, const int* __restrict__ blk_sum,
                           int* __restrict__ row_ptr) {
    __shared__ int wtot[16];
    __shared__ int wpre[16];
    int b = blockIdx.x, t = threadIdx.x;
    int lane = t & 63, wid = t >> 6;
    int i0 = b * 4096 + t * 4;
    int x0 = (i0 + 0 < N_NODES) ? counts[i0 + 0] : 0;
    int x1 = (i0 + 1 < N_NODES) ? counts[i0 + 1] : 0;
    int x2 = (i0 + 2 < N_NODES) ? counts[i0 + 2] : 0;
    int x3 = (i0 + 3 < N_NODES) ? counts[i0 + 3] : 0;
    int tsum = x0 + x1 + x2 + x3;
    int v = tsum;
    #pragma unroll
    for (int off = 1; off < 64; off <<= 1) {
        int u = __shfl_up(v, off, 64);
        if (lane >= off) v += u;
    }
    if (lane == 63) wtot[wid] = v;
    __syncthreads();
    if (wid == 0) {
        int wv = (lane < 16) ? wtot[lane] : 0;
        #pragma unroll
        for (int off = 1; off < 16; off <<= 1) {
            int u = __shfl_up(wv, off, 64);
            if (lane >= off) wv += u;
        }
        if (lane < 16) wpre[lane] = wv;
    }
    __syncthreads();
    int wbase = (wid == 0) ? 0 : wpre[wid - 1];
    int ex = blk_sum[b] + wbase + (v - tsum);
    if (i0 + 0 < N_NODES) row_ptr[i0 + 0] = ex;
    if (i0 + 1 < N_NODES) row_ptr[i0 + 1] = ex + x0;
    if (i0 + 2 < N_NODES) row_ptr[i0 + 2] = ex + x0 + x1;
    if (i0 + 3 < N_NODES) row_ptr[i0 + 3] = ex + x0 + x1 + x2;
}

// one packed 8B scatter per edge: [eid:32 | rel:16 | src:16]
__global__ void scatter_kernel(const int* __restrict__ src, const int* __restrict__ dst,
                               const int* __restrict__ rel, const int* __restrict__ row_ptr,
                               int* __restrict__ cursor, u64* __restrict__ sorted_pack) {
    int t = blockIdx.x * 256 + threadIdx.x;
    if (t >= N_EDGE) return;
    int d = dst[t];
    int pos = row_ptr[d] + atomicAdd(&cursor[d], 1);
    sorted_pack[pos] = ((u64)(unsigned)t << 32) | ((unsigned)rel[t] << 16) | (unsigned)src[t];
}

// ---------------------------------------------------------------- dense pieces
// C[n,64] = A[n,64] @ W[64,64], 32 rows per block  (round-1 proven structure)
__global__ void gemm64(const float* __restrict__ A, const float* __restrict__ W,
                       float* __restrict__ C, int n) {
    __shared__ float Ws[64][64];
    __shared__ float As[32][64];
    int t = threadIdx.x;      // 256
    for (int i = t; i < 64 * 64; i += 256) Ws[i >> 6][i & 63] = W[i];
    int row0 = blockIdx.x * 32;
    for (int i = t; i < 32 * 64; i += 256) {
        int r = i >> 6, c = i & 63;
        int gr = row0 + r;
        As[r][c] = (gr < n) ? A[(size_t)gr * 64 + c] : 0.f;
    }
    __syncthreads();
    int col = t & 63;
    int r0 = t >> 6;
    for (int r = r0; r < 32; r += 4) {
        float acc = 0.f;
        #pragma unroll
        for (int k = 0; k < 64; ++k) acc += As[r][k] * Ws[k][col];
        int gr = row0 + r;
        if (gr < n) C[(size_t)gr * 64 + col] = acc;
    }
}

// s_src[n,h] = dot(feat0[n,h,:], a0[h,:]); s_dst likewise with a1
__global__ void node_scores(const float* __restrict__ feat0, const float* __restrict__ a,
                            float* __restrict__ s_src, float* __restrict__ s_dst) {
    int t = blockIdx.x * 256 + threadIdx.x;
    if (t >= N_NODES * HEADS) return;
    int n = t >> 2, h = t & 3;
    const float* f  = feat0 + (size_t)n * 64 + h * 16;
    const float* a0 = a + h * 16;              // a[0][h][:]
    const float* a1 = a + HEADS * DH + h * 16; // a[1][h][:]
    float ss = 0.f, sd = 0.f;
    #pragma unroll
    for (int d = 0; d < 16; ++d) { float v = f[d]; ss += v * a0[d]; sd += v * a1[d]; }
    s_src[t] = ss; s_dst[t] = sd;
}

// s_rel[r,h] = dot((rel_emb @ W_rel)[r, h*16:...], a2[h,:])
__global__ void rel_scores(const float* __restrict__ rel_emb, const float* __restrict__ Wr,
                           const float* __restrict__ a2, float* __restrict__ s_rel) {
    __shared__ float proj[64];
    int r = blockIdx.x, c = threadIdx.x;   // 64 threads
    float acc = 0.f;
    #pragma unroll
    for (int k = 0; k < 64; ++k) acc += rel_emb[(size_t)r * 64 + k] * Wr[k * 64 + c];
    proj[c] = acc;
    __syncthreads();
    if (c < HEADS) {
        float s = 0.f;
        #pragma unroll
        for (int d = 0; d < 16; ++d) s += proj[c * 16 + d] * a2[c * 16 + d];
        s_rel[r * HEADS + c] = s;
    }
}

// ---------------------------------------------------------------- edge scores (edge-parallel)
__global__ void edge_scores(const u64* __restrict__ pack, const float* __restrict__ s_src,
                            const float* __restrict__ s_rel, float4* __restrict__ sc) {
    int j = blockIdx.x * 256 + threadIdx.x;
    if (j >= N_EDGE) return;
    u64 p = pack[j];
    int src = (int)(p & 0xFFFF);
    int rel = (int)((p >> 16) & 0xFFFF);
    float4 a = *(const float4*)(s_src + (size_t)src * 4);
    float4 b = *(const float4*)(s_rel + (size_t)rel * 4);
    sc[j] = make_float4(a.x + b.x, a.y + b.y, a.z + b.z, a.w + b.w);
}

// ---------------------------------------------------------------- top-k + softmax (streaming)
__global__ void topk_kernel(const int* __restrict__ row_ptr, const u64* __restrict__ pack,
                            const float* __restrict__ sc, const float* __restrict__ s_dst,
                            int* __restrict__ kept_src, float* __restrict__ kept_w,
                            int* __restrict__ kept_cnt) {
    int t = blockIdx.x * 256 + threadIdx.x;
    if (t >= N_NODES * HEADS) return;
    int d = t >> 2, h = t & 3;
    int beg = row_ptr[d], end = row_ptr[d + 1];
    float sdst = s_dst[t];

    float topS[TOPK]; int topI[TOPK]; int topN[TOPK];
    #pragma unroll
    for (int i = 0; i < TOPK; ++i) { topS[i] = -3.4e38f; topI[i] = 0x7fffffff; topN[i] = 0; }

    for (int j = beg; j < end; ++j) {
        float s = sc[(size_t)j * 4 + h] + sdst;
        s = s > 0.f ? s : SLOPE * s;          // leaky relu
        if (s < topS[TOPK - 1]) continue;     // early-out vs current slot 9
        u64 p = pack[j];
        int id = (int)(p >> 32);
        int sn = (int)(p & 0xFFFF);
        if (s == topS[TOPK - 1] && id > topI[TOPK - 1]) continue;
        #pragma unroll
        for (int i = 0; i < TOPK; ++i) {      // rank by (score desc, edge id asc)
            bool better = (s > topS[i]) || (s == topS[i] && id < topI[i]);
            if (better) {
                float ts = topS[i]; int ti = topI[i]; int tn = topN[i];
                topS[i] = s; topI[i] = id; topN[i] = sn;
                s = ts; id = ti; sn = tn;
            }
        }
    }
    int deg = end - beg;
    int cnt = deg < TOPK ? deg : TOPK;
    float m = (cnt > 0) ? topS[0] : 0.f;
    float w[TOPK]; float den = 0.f;
    #pragma unroll
    for (int i = 0; i < TOPK; ++i) {
        float e = (i < cnt) ? expf(topS[i] - m) : 0.f;
        w[i] = e; den += e;
    }
    float inv = 1.f / (den + 1e-16f);
    #pragma unroll
    for (int i = 0; i < TOPK; ++i) {
        kept_w[(size_t)t * TOPK + i]   = (i < cnt) ? w[i] * inv : 0.f;
        kept_src[(size_t)t * TOPK + i] = topN[i];
    }
    kept_cnt[t] = cnt;
}

// ---------------------------------------------------------------- diffusion hop (float4)
// 256 threads = 16 nodes x 16 float4-lanes
template<bool FINAL>
__global__ void hop_kernel(const float4* __restrict__ hc_in, const float4* __restrict__ feat0,
                           const int* __restrict__ kept_src, const float* __restrict__ kept_w,
                           const int* __restrict__ kept_cnt,
                           const float4* __restrict__ res, float4* __restrict__ out) {
    __shared__ int   ls[16 * HEADS * TOPK];
    __shared__ float lw[16 * HEADS * TOPK];
    __shared__ int   lc[16 * HEADS];
    int tb = threadIdx.x;            // 256
    int nb = blockIdx.x * 16;        // first node
    for (int i = tb; i < 16 * HEADS * TOPK; i += 256) {
        int idx = nb * HEADS * TOPK + i;
        ls[i] = kept_src[idx];
        lw[i] = kept_w[idx];
    }
    if (tb < 16 * HEADS) lc[tb] = kept_cnt[nb * HEADS + tb];
    __syncthreads();
    int nl = tb >> 4;                // node in block
    int c4 = tb & 15;                // float4 column
    int h  = c4 >> 2;
    int lbase = nl * HEADS * TOPK + h * TOPK;
    int cnt = lc[nl * HEADS + h];
    float4 acc = make_float4(0.f, 0.f, 0.f, 0.f);
    for (int k = 0; k < cnt; ++k) {
        float w = lw[lbase + k];
        int s = ls[lbase + k];
        float4 v = hc_in[(size_t)s * 16 + c4];
        acc.x += w * v.x; acc.y += w * v.y; acc.z += w * v.z; acc.w += w * v.w;
    }
    size_t o = (size_t)nb * 16 + tb;
    float4 f = feat0[o];
    float4 r;
    r.x = (1.f - ALPHA) * acc.x + ALPHA * f.x;
    r.y = (1.f - ALPHA) * acc.y + ALPHA * f.y;
    r.z = (1.f - ALPHA) * acc.z + ALPHA * f.z;
    r.w = (1.f - ALPHA) * acc.w + ALPHA * f.w;
    if (FINAL) {
        float4 rs = res[o];
        float x;
        x = r.x + rs.x; r.x = x > 0.f ? x : (expf(x) - 1.f);
        x = r.y + rs.y; r.y = x > 0.f ? x : (expf(x) - 1.f);
        x = r.z + rs.z; r.z = x > 0.f ? x : (expf(x) - 1.f);
        x = r.w + rs.w; r.w = x > 0.f ? x : (expf(x) - 1.f);
    }
    out[o] = r;
}

// ---------------------------------------------------------------- rel output
__global__ void relout_kernel(const float* __restrict__ rel_emb, const float* __restrict__ Wf,
                              float* __restrict__ out) {
    int r = blockIdx.x, c = threadIdx.x;  // 500 x 64
    float acc = 0.f;
    #pragma unroll
    for (int k = 0; k < 64; ++k) acc += rel_emb[(size_t)r * 64 + k] * Wf[k * 64 + c];
    out[(size_t)r * 64 + c] = acc;
}

// ---------------------------------------------------------------- launch
extern "C" void kernel_launch(void* const* d_in, const int* in_sizes, int n_in,
                              void* d_out, int out_size, void* d_ws, size_t ws_size,
                              hipStream_t stream) {
    (void)in_sizes; (void)n_in; (void)out_size; (void)ws_size;
    const float* ent_emb  = (const float*)d_in[0];
    const float* rel_emb  = (const float*)d_in[1];
    const int*   edge_src = (const int*)d_in[2];
    const int*   edge_dst = (const int*)d_in[3];
    const int*   edge_rel = (const int*)d_in[4];
    const float* W_ent    = (const float*)d_in[5];
    const float* W_rel    = (const float*)d_in[6];
    const float* attn_a   = (const float*)d_in[7];
    const float* res_W    = (const float*)d_in[8];
    const float* fc_rel_w = (const float*)d_in[9];

    char* wp = (char*)d_ws;
    auto alloc = [&](size_t bytes) -> void* {
        void* p = (void*)wp;
        wp += (bytes + 255) & ~(size_t)255;
        return p;
    };
    int*   counts     = (int*)alloc((size_t)N_NODES * 4);
    int*   cursor     = (int*)alloc((size_t)N_NODES * 4);
    int*   row_ptr    = (int*)alloc((size_t)(N_NODES + 1) * 4);
    int*   blk_sum    = (int*)alloc((size_t)SCAN_NBLK * 4);
    u64*   sorted_pack= (u64*)alloc((size_t)N_EDGE * 8);
    float* s_src      = (float*)alloc((size_t)N_NODES * HEADS * 4);
    float* s_dst      = (float*)alloc((size_t)N_NODES * HEADS * 4);
    float* s_rel      = (float*)alloc((size_t)N_RELS * HEADS * 4);
    float* feat0      = (float*)alloc((size_t)N_NODES * HID * 4);
    float* hcA        = (float*)alloc((size_t)N_NODES * HID * 4);
    float* hcB        = (float*)alloc((size_t)N_NODES * HID * 4);   // aliased as sc_sorted
    float* res        = (float*)alloc((size_t)N_NODES * HID * 4);
    int*   kept_src   = (int*)alloc((size_t)N_NODES * HEADS * TOPK * 4);
    float* kept_w     = (float*)alloc((size_t)N_NODES * HEADS * TOPK * 4);
    int*   kept_cnt   = (int*)alloc((size_t)N_NODES * HEADS * 4);
    float4* sc_sorted = (float4*)hcB;   // E*16B == N*HID*4B == 12.8 MB, disjoint lifetime

    // ---- CSR by destination (edges are layer-invariant: build once) ----
    hipMemsetAsync(counts, 0, (size_t)N_NODES * 4, stream);
    hipMemsetAsync(cursor, 0, (size_t)N_NODES * 4, stream);
    hist_kernel<<<N_EDGE / 256, 256, 0, stream>>>(edge_dst, counts);
    scan_partial<<<SCAN_NBLK, 1024, 0, stream>>>(counts, blk_sum);
    scan_small<<<1, 64, 0, stream>>>(blk_sum, row_ptr);
    scan_final<<<SCAN_NBLK, 1024, 0, stream>>>(counts, blk_sum, row_ptr);
    scatter_kernel<<<N_EDGE / 256, 256, 0, stream>>>(edge_src, edge_dst, edge_rel, row_ptr,
                                                     cursor, sorted_pack);

    float* out_h = (float*)d_out;     // node rows; layer-1 output also lives here
    const float* h = ent_emb;
    const int nb_gemm = (N_NODES + 31) / 32;
    const int nb_nh   = (N_NODES * HEADS + 255) / 256;
    const int nb_edge = (N_EDGE + 255) / 256;
    const int nb_hop  = N_NODES / 16;   // 3125, exact

    for (int l = 0; l < LAYERS; ++l) {
        const float* We = W_ent + (size_t)l * HID * HID;
        const float* Wr = W_rel + (size_t)l * HID * HID;
        const float* a  = attn_a + (size_t)l * 3 * HEADS * DH;
        const float* rW = res_W + (size_t)l * HID * HID;

        gemm64<<<nb_gemm, 256, 0, stream>>>(h, We, feat0, N_NODES);
        node_scores<<<nb_nh, 256, 0, stream>>>(feat0, a, s_src, s_dst);
        rel_scores<<<N_RELS, 64, 0, stream>>>(rel_emb, Wr, a + 2 * HEADS * DH, s_rel);
        edge_scores<<<nb_edge, 256, 0, stream>>>(sorted_pack, s_src, s_rel, sc_sorted);
        topk_kernel<<<nb_nh, 256, 0, stream>>>(row_ptr, sorted_pack, (const float*)sc_sorted,
                                               s_dst, kept_src, kept_w, kept_cnt);
        gemm64<<<nb_gemm, 256, 0, stream>>>(h, rW, res, N_NODES);
        hop_kernel<false><<<nb_hop, 256, 0, stream>>>((const float4*)feat0, (const float4*)feat0,
                                                      kept_src, kept_w, kept_cnt, nullptr, (float4*)hcA);
        hop_kernel<false><<<nb_hop, 256, 0, stream>>>((const float4*)hcA, (const float4*)feat0,
                                                      kept_src, kept_w, kept_cnt, nullptr, (float4*)hcB);
        hop_kernel<true><<<nb_hop, 256, 0, stream>>>((const float4*)hcB, (const float4*)feat0,
                                                     kept_src, kept_w, kept_cnt, (const float4*)res,
                                                     (float4*)out_h);
        h = out_h;
    }
    relout_kernel<<<N_RELS, 64, 0, stream>>>(rel_emb, fc_rel_w, (float*)d_out + (size_t)N_NODES * HID);
}

// Round 4
// 408.503 us; speedup vs baseline: 5.8676x; 1.2302x over previous
//
#include <hip/hip_runtime.h>
#include <math.h>

#define N_NODES 50000
#define N_RELS  500
#define N_EDGE  800000
#define HID     64
#define HEADS   4
#define DH      16
#define LAYERS  2
#define HOPS    3
#define TOPK    10
#define ALPHA   0.15f
#define SLOPE   0.2f

#define SCAN_NBLK 13   // ceil(50000/4096)

typedef unsigned long long u64;

// ---------------------------------------------------------------- CSR build
__global__ void hist_kernel(const int* __restrict__ dst, int* __restrict__ counts) {
    int t = blockIdx.x * 256 + threadIdx.x;
    if (t < N_EDGE) atomicAdd(&counts[dst[t]], 1);
}

// block partial sums: 13 blocks x 1024 threads x 4 elems
__global__ void scan_partial(const int* __restrict__ counts, int* __restrict__ blk_sum) {
    int t = threadIdx.x, b = blockIdx.x;
    int i0 = b * 4096 + t * 4;
    int s = 0;
    #pragma unroll
    for (int q = 0; q < 4; ++q) { int i = i0 + q; if (i < N_NODES) s += counts[i]; }
    #pragma unroll
    for (int off = 32; off > 0; off >>= 1) s += __shfl_down(s, off, 64);
    __shared__ int ws[16];
    if ((t & 63) == 0) ws[t >> 6] = s;
    __syncthreads();
    if (t == 0) { int tot = 0; for (int i = 0; i < 16; ++i) tot += ws[i]; blk_sum[b] = tot; }
}

__global__ void scan_small(int* __restrict__ blk_sum, int* __restrict__ row_ptr) {
    if (threadIdx.x == 0) {
        int acc = 0;
        for (int i = 0; i < SCAN_NBLK; ++i) { int v = blk_sum[i]; blk_sum[i] = acc; acc += v; }
        row_ptr[N_NODES] = acc;   // == N_EDGE
    }
}

__global__ void scan_final(const int* __restrict__ counts, const int* __restrict__ blk_sum,
                           int* __restrict__ row_ptr) {
    __shared__ int wtot[16];
    __shared__ int wpre[16];
    int b = blockIdx.x, t = threadIdx.x;
    int lane = t & 63, wid = t >> 6;
    int i0 = b * 4096 + t * 4;
    int x0 = (i0 + 0 < N_NODES) ? counts[i0 + 0] : 0;
    int x1 = (i0 + 1 < N_NODES) ? counts[i0 + 1] : 0;
    int x2 = (i0 + 2 < N_NODES) ? counts[i0 + 2] : 0;
    int x3 = (i0 + 3 < N_NODES) ? counts[i0 + 3] : 0;
    int tsum = x0 + x1 + x2 + x3;
    int v = tsum;
    #pragma unroll
    for (int off = 1; off < 64; off <<= 1) {
        int u = __shfl_up(v, off, 64);
        if (lane >= off) v += u;
    }
    if (lane == 63) wtot[wid] = v;
    __syncthreads();
    if (wid == 0) {
        int wv = (lane < 16) ? wtot[lane] : 0;
        #pragma unroll
        for (int off = 1; off < 16; off <<= 1) {
            int u = __shfl_up(wv, off, 64);
            if (lane >= off) wv += u;
        }
        if (lane < 16) wpre[lane] = wv;
    }
    __syncthreads();
    int wbase = (wid == 0) ? 0 : wpre[wid - 1];
    int ex = blk_sum[b] + wbase + (v - tsum);
    if (i0 + 0 < N_NODES) row_ptr[i0 + 0] = ex;
    if (i0 + 1 < N_NODES) row_ptr[i0 + 1] = ex + x0;
    if (i0 + 2 < N_NODES) row_ptr[i0 + 2] = ex + x0 + x1;
    if (i0 + 3 < N_NODES) row_ptr[i0 + 3] = ex + x0 + x1 + x2;
}

// cursor pre-initialized to row_ptr: single atomic gives slot directly
__global__ void scatter_kernel(const int* __restrict__ src, const int* __restrict__ dst,
                               const int* __restrict__ rel,
                               int* __restrict__ cursor, u64* __restrict__ sorted_pack) {
    int t = blockIdx.x * 256 + threadIdx.x;
    if (t >= N_EDGE) return;
    int d = dst[t];
    int pos = atomicAdd(&cursor[d], 1);
    sorted_pack[pos] = ((u64)(unsigned)t << 32) | ((unsigned)rel[t] << 16) | (unsigned)src[t];
}

// ---------------------------------------------------------------- dense pieces
// C1 = A@W1, C2 = A@W2; 32 rows/block; thread = (row-slot, col-quad), float4 accs
__global__ __launch_bounds__(256) void gemm_dual(
        const float* __restrict__ A, const float* __restrict__ W1, const float* __restrict__ W2,
        float* __restrict__ C1, float* __restrict__ C2, int n) {
    __shared__ float W1s[64][64];   // [k][c]
    __shared__ float W2s[64][64];
    __shared__ float As[32][64];
    int t = threadIdx.x;      // 256
    const float4* W1v = (const float4*)W1;
    const float4* W2v = (const float4*)W2;
    for (int i = t; i < 1024; i += 256) {
        ((float4*)W1s)[i] = W1v[i];
        ((float4*)W2s)[i] = W2v[i];
    }
    int row0 = blockIdx.x * 32;
    const float4* Av = (const float4*)A;
    for (int i = t; i < 512; i += 256) {       // 32 rows * 16 float4
        int gr = row0 + (i >> 4);
        ((float4*)As)[i] = (gr < n) ? Av[(size_t)row0 * 16 + i] : make_float4(0.f, 0.f, 0.f, 0.f);
    }
    __syncthreads();
    int cq = (t & 15) * 4;     // column quad base
    int rs = t >> 4;           // row slot: rows rs and rs+16
    float4 a1a = make_float4(0.f,0.f,0.f,0.f), a1b = a1a, a2a = a1a, a2b = a1a;
    #pragma unroll 4
    for (int k = 0; k < 64; ++k) {
        float va = As[rs][k];
        float vb = As[rs + 16][k];
        float4 w1 = *(const float4*)&W1s[k][cq];
        float4 w2 = *(const float4*)&W2s[k][cq];
        a1a.x += va * w1.x; a1a.y += va * w1.y; a1a.z += va * w1.z; a1a.w += va * w1.w;
        a2a.x += va * w2.x; a2a.y += va * w2.y; a2a.z += va * w2.z; a2a.w += va * w2.w;
        a1b.x += vb * w1.x; a1b.y += vb * w1.y; a1b.z += vb * w1.z; a1b.w += vb * w1.w;
        a2b.x += vb * w2.x; a2b.y += vb * w2.y; a2b.z += vb * w2.z; a2b.w += vb * w2.w;
    }
    int gra = row0 + rs, grb = row0 + rs + 16;
    if (gra < n) {
        *(float4*)&C1[(size_t)gra * 64 + cq] = a1a;
        *(float4*)&C2[(size_t)gra * 64 + cq] = a2a;
    }
    if (grb < n) {
        *(float4*)&C1[(size_t)grb * 64 + cq] = a1b;
        *(float4*)&C2[(size_t)grb * 64 + cq] = a2b;
    }
}

// s_src[n,h] = dot(feat0[n,h,:], a0[h,:]); s_dst likewise with a1
__global__ void node_scores(const float* __restrict__ feat0, const float* __restrict__ a,
                            float* __restrict__ s_src, float* __restrict__ s_dst) {
    int t = blockIdx.x * 256 + threadIdx.x;
    if (t >= N_NODES * HEADS) return;
    int n = t >> 2, h = t & 3;
    const float* f  = feat0 + (size_t)n * 64 + h * 16;
    const float* a0 = a + h * 16;              // a[0][h][:]
    const float* a1 = a + HEADS * DH + h * 16; // a[1][h][:]
    float ss = 0.f, sd = 0.f;
    #pragma unroll
    for (int d = 0; d < 16; ++d) { float v = f[d]; ss += v * a0[d]; sd += v * a1[d]; }
    s_src[t] = ss; s_dst[t] = sd;
}

// s_rel[r,h] = dot((rel_emb @ W_rel)[r, h*16:...], a2[h,:])
__global__ void rel_scores(const float* __restrict__ rel_emb, const float* __restrict__ Wr,
                           const float* __restrict__ a2, float* __restrict__ s_rel) {
    __shared__ float proj[64];
    int r = blockIdx.x, c = threadIdx.x;   // 64 threads
    float acc = 0.f;
    #pragma unroll
    for (int k = 0; k < 64; ++k) acc += rel_emb[(size_t)r * 64 + k] * Wr[k * 64 + c];
    proj[c] = acc;
    __syncthreads();
    if (c < HEADS) {
        float s = 0.f;
        #pragma unroll
        for (int d = 0; d < 16; ++d) s += proj[c * 16 + d] * a2[c * 16 + d];
        s_rel[r * HEADS + c] = s;
    }
}

// ---------------------------------------------------------------- edge scores (head-major planes)
__global__ void edge_scores(const u64* __restrict__ pack, const float* __restrict__ s_src,
                            const float* __restrict__ s_rel, float* __restrict__ sc) {
    int j = blockIdx.x * 256 + threadIdx.x;
    if (j >= N_EDGE) return;
    u64 p = pack[j];
    int src = (int)(p & 0xFFFF);
    int rel = (int)((p >> 16) & 0xFFFF);
    float4 a = *(const float4*)(s_src + (size_t)src * 4);
    float4 b = *(const float4*)(s_rel + (size_t)rel * 4);
    sc[0 * N_EDGE + j] = a.x + b.x;
    sc[1 * N_EDGE + j] = a.y + b.y;
    sc[2 * N_EDGE + j] = a.z + b.z;
    sc[3 * N_EDGE + j] = a.w + b.w;
}

// ---------------------------------------------------------------- top-k + softmax (streaming)
// selects on RAW sc (lrelu(x+sdst) is strictly monotone -> same order & ties);
// transform applied only to the <=10 survivors.
__global__ void topk_kernel(const int* __restrict__ row_ptr, const u64* __restrict__ pack,
                            const float* __restrict__ sc_all, const float* __restrict__ s_dst,
                            int* __restrict__ kept_src, float* __restrict__ kept_w,
                            int* __restrict__ kept_cnt) {
    int t = blockIdx.x * 256 + threadIdx.x;
    if (t >= N_NODES * HEADS) return;
    int d = t >> 2, h = t & 3;
    int beg = row_ptr[d], end = row_ptr[d + 1];
    const float* sc = sc_all + (size_t)h * N_EDGE;

    float topS[TOPK]; int topI[TOPK]; int topN[TOPK];
    #pragma unroll
    for (int i = 0; i < TOPK; ++i) { topS[i] = -3.4e38f; topI[i] = 0x7fffffff; topN[i] = 0; }

    auto ins = [&](float s, int j) {
        if (s < topS[TOPK - 1]) return;
        u64 p = pack[j];
        int id = (int)(p >> 32);
        int sn = (int)(p & 0xFFFF);
        if (s == topS[TOPK - 1] && id > topI[TOPK - 1]) return;
        #pragma unroll
        for (int i = 0; i < TOPK; ++i) {      // rank by (score desc, edge id asc)
            bool better = (s > topS[i]) || (s == topS[i] && id < topI[i]);
            if (better) {
                float ts = topS[i]; int ti = topI[i]; int tn = topN[i];
                topS[i] = s; topI[i] = id; topN[i] = sn;
                s = ts; id = ti; sn = tn;
            }
        }
    };

    int j = beg;
    for (; j + 4 <= end; j += 4) {
        float s0 = sc[j + 0];
        float s1 = sc[j + 1];
        float s2 = sc[j + 2];
        float s3 = sc[j + 3];
        float mx = fmaxf(fmaxf(s0, s1), fmaxf(s2, s3));
        if (mx < topS[TOPK - 1]) continue;    // whole batch below slot 9
        ins(s0, j + 0); ins(s1, j + 1); ins(s2, j + 2); ins(s3, j + 3);
    }
    for (; j < end; ++j) ins(sc[j], j);

    int deg = end - beg;
    int cnt = deg < TOPK ? deg : TOPK;
    float sdst = s_dst[t];
    float tm = topS[0] + sdst;
    tm = tm > 0.f ? tm : SLOPE * tm;          // transformed max (monotone => max of transformed)
    float w[TOPK]; float den = 0.f;
    #pragma unroll
    for (int i = 0; i < TOPK; ++i) {
        float ti = topS[i] + sdst;
        ti = ti > 0.f ? ti : SLOPE * ti;
        float e = (i < cnt) ? expf(ti - tm) : 0.f;
        w[i] = e; den += e;
    }
    float inv = 1.f / (den + 1e-16f);
    #pragma unroll
    for (int i = 0; i < TOPK; ++i) {
        kept_w[(size_t)t * TOPK + i]   = (i < cnt) ? w[i] * inv : 0.f;
        kept_src[(size_t)t * TOPK + i] = topN[i];
    }
    kept_cnt[t] = cnt;
}

// ---------------------------------------------------------------- diffusion hop (float4)
// 256 threads = 16 nodes x 16 float4-lanes
template<bool FINAL>
__global__ void hop_kernel(const float4* __restrict__ hc_in, const float4* __restrict__ feat0,
                           const int* __restrict__ kept_src, const float* __restrict__ kept_w,
                           const int* __restrict__ kept_cnt,
                           const float4* __restrict__ res, float4* __restrict__ out) {
    __shared__ int   ls[16 * HEADS * TOPK];
    __shared__ float lw[16 * HEADS * TOPK];
    __shared__ int   lc[16 * HEADS];
    int tb = threadIdx.x;            // 256
    int nb = blockIdx.x * 16;        // first node
    for (int i = tb; i < 16 * HEADS * TOPK; i += 256) {
        int idx = nb * HEADS * TOPK + i;
        ls[i] = kept_src[idx];
        lw[i] = kept_w[idx];
    }
    if (tb < 16 * HEADS) lc[tb] = kept_cnt[nb * HEADS + tb];
    __syncthreads();
    int nl = tb >> 4;                // node in block
    int c4 = tb & 15;                // float4 column
    int h  = c4 >> 2;
    int lbase = nl * HEADS * TOPK + h * TOPK;
    int cnt = lc[nl * HEADS + h];
    float4 acc = make_float4(0.f, 0.f, 0.f, 0.f);
    for (int k = 0; k < cnt; ++k) {
        float w = lw[lbase + k];
        int s = ls[lbase + k];
        float4 v = hc_in[(size_t)s * 16 + c4];
        acc.x += w * v.x; acc.y += w * v.y; acc.z += w * v.z; acc.w += w * v.w;
    }
    size_t o = (size_t)nb * 16 + tb;
    float4 f = feat0[o];
    float4 r;
    r.x = (1.f - ALPHA) * acc.x + ALPHA * f.x;
    r.y = (1.f - ALPHA) * acc.y + ALPHA * f.y;
    r.z = (1.f - ALPHA) * acc.z + ALPHA * f.z;
    r.w = (1.f - ALPHA) * acc.w + ALPHA * f.w;
    if (FINAL) {
        float4 rs = res[o];
        float x;
        x = r.x + rs.x; r.x = x > 0.f ? x : (expf(x) - 1.f);
        x = r.y + rs.y; r.y = x > 0.f ? x : (expf(x) - 1.f);
        x = r.z + rs.z; r.z = x > 0.f ? x : (expf(x) - 1.f);
        x = r.w + rs.w; r.w = x > 0.f ? x : (expf(x) - 1.f);
    }
    out[o] = r;
}

// ---------------------------------------------------------------- rel output
__global__ void relout_kernel(const float* __restrict__ rel_emb, const float* __restrict__ Wf,
                              float* __restrict__ out) {
    int r = blockIdx.x, c = threadIdx.x;  // 500 x 64
    float acc = 0.f;
    #pragma unroll
    for (int k = 0; k < 64; ++k) acc += rel_emb[(size_t)r * 64 + k] * Wf[k * 64 + c];
    out[(size_t)r * 64 + c] = acc;
}

// ---------------------------------------------------------------- launch
extern "C" void kernel_launch(void* const* d_in, const int* in_sizes, int n_in,
                              void* d_out, int out_size, void* d_ws, size_t ws_size,
                              hipStream_t stream) {
    (void)in_sizes; (void)n_in; (void)out_size; (void)ws_size;
    const float* ent_emb  = (const float*)d_in[0];
    const float* rel_emb  = (const float*)d_in[1];
    const int*   edge_src = (const int*)d_in[2];
    const int*   edge_dst = (const int*)d_in[3];
    const int*   edge_rel = (const int*)d_in[4];
    const float* W_ent    = (const float*)d_in[5];
    const float* W_rel    = (const float*)d_in[6];
    const float* attn_a   = (const float*)d_in[7];
    const float* res_W    = (const float*)d_in[8];
    const float* fc_rel_w = (const float*)d_in[9];

    char* wp = (char*)d_ws;
    auto alloc = [&](size_t bytes) -> void* {
        void* p = (void*)wp;
        wp += (bytes + 255) & ~(size_t)255;
        return p;
    };
    int*   counts     = (int*)alloc((size_t)N_NODES * 4);
    int*   cursor     = (int*)alloc((size_t)N_NODES * 4);
    int*   row_ptr    = (int*)alloc((size_t)(N_NODES + 1) * 4);
    int*   blk_sum    = (int*)alloc((size_t)SCAN_NBLK * 4);
    u64*   sorted_pack= (u64*)alloc((size_t)N_EDGE * 8);
    float* s_src      = (float*)alloc((size_t)N_NODES * HEADS * 4);
    float* s_dst      = (float*)alloc((size_t)N_NODES * HEADS * 4);
    float* s_rel      = (float*)alloc((size_t)N_RELS * HEADS * 4);
    float* feat0      = (float*)alloc((size_t)N_NODES * HID * 4);
    float* hcA        = (float*)alloc((size_t)N_NODES * HID * 4);
    float* hcB        = (float*)alloc((size_t)N_NODES * HID * 4);   // aliased as sc planes
    float* res        = (float*)alloc((size_t)N_NODES * HID * 4);
    int*   kept_src   = (int*)alloc((size_t)N_NODES * HEADS * TOPK * 4);
    float* kept_w     = (float*)alloc((size_t)N_NODES * HEADS * TOPK * 4);
    int*   kept_cnt   = (int*)alloc((size_t)N_NODES * HEADS * 4);
    float* sc_planes  = hcB;   // 4 * E * 4B == N*HID*4B == 12.8 MB, disjoint lifetime

    // ---- CSR by destination (edges are layer-invariant: build once) ----
    hipMemsetAsync(counts, 0, (size_t)N_NODES * 4, stream);
    hist_kernel<<<N_EDGE / 256, 256, 0, stream>>>(edge_dst, counts);
    scan_partial<<<SCAN_NBLK, 1024, 0, stream>>>(counts, blk_sum);
    scan_small<<<1, 64, 0, stream>>>(blk_sum, row_ptr);
    scan_final<<<SCAN_NBLK, 1024, 0, stream>>>(counts, blk_sum, row_ptr);
    hipMemcpyAsync(cursor, row_ptr, (size_t)N_NODES * 4, hipMemcpyDeviceToDevice, stream);
    scatter_kernel<<<N_EDGE / 256, 256, 0, stream>>>(edge_src, edge_dst, edge_rel,
                                                     cursor, sorted_pack);

    float* out_h = (float*)d_out;     // node rows; layer-1 output also lives here
    const float* h = ent_emb;
    const int nb_gemm = (N_NODES + 31) / 32;
    const int nb_nh   = (N_NODES * HEADS + 255) / 256;
    const int nb_edge = (N_EDGE + 255) / 256;
    const int nb_hop  = N_NODES / 16;   // 3125, exact

    for (int l = 0; l < LAYERS; ++l) {
        const float* We = W_ent + (size_t)l * HID * HID;
        const float* Wr = W_rel + (size_t)l * HID * HID;
        const float* a  = attn_a + (size_t)l * 3 * HEADS * DH;
        const float* rW = res_W + (size_t)l * HID * HID;

        gemm_dual<<<nb_gemm, 256, 0, stream>>>(h, We, rW, feat0, res, N_NODES);
        node_scores<<<nb_nh, 256, 0, stream>>>(feat0, a, s_src, s_dst);
        rel_scores<<<N_RELS, 64, 0, stream>>>(rel_emb, Wr, a + 2 * HEADS * DH, s_rel);
        edge_scores<<<nb_edge, 256, 0, stream>>>(sorted_pack, s_src, s_rel, sc_planes);
        topk_kernel<<<nb_nh, 256, 0, stream>>>(row_ptr, sorted_pack, sc_planes,
                                               s_dst, kept_src, kept_w, kept_cnt);
        hop_kernel<false><<<nb_hop, 256, 0, stream>>>((const float4*)feat0, (const float4*)feat0,
                                                      kept_src, kept_w, kept_cnt, nullptr, (float4*)hcA);
        hop_kernel<false><<<nb_hop, 256, 0, stream>>>((const float4*)hcA, (const float4*)feat0,
                                                      kept_src, kept_w, kept_cnt, nullptr, (float4*)hcB);
        hop_kernel<true><<<nb_hop, 256, 0, stream>>>((const float4*)hcB, (const float4*)feat0,
                                                     kept_src, kept_w, kept_cnt, (const float4*)res,
                                                     (float4*)out_h);
        h = out_h;
    }
    relout_kernel<<<N_RELS, 64, 0, stream>>>(rel_emb, fc_rel_w, (float*)d_out + (size_t)N_NODES * HID);
}

// Round 5
// 372.709 us; speedup vs baseline: 6.4311x; 1.0960x over previous
//
#include <hip/hip_runtime.h>
#include <math.h>

#define N_NODES 50000
#define N_RELS  500
#define N_EDGE  800000
#define HID     64
#define HEADS   4
#define DH      16
#define LAYERS  2
#define HOPS    3
#define TOPK    10
#define ALPHA   0.15f
#define SLOPE   0.2f

#define SCAN_NBLK 13        // ceil(50000/4096)
#define NBUCK 64
#define DST_PER_BUCK 784    // 64*784 = 50176 >= 50000
#define L1_EDGES 4096       // edges per level-1 block
#define L1_NBLK ((N_EDGE + L1_EDGES - 1) / L1_EDGES)   // 196

typedef unsigned long long u64;

// pack layout: [eid:20 (bits 42..61) | dst:16 (26..41) | rel:10 (16..25) | src:16 (0..15)]
#define PK_SRC(p)  ((int)((p) & 0xFFFF))
#define PK_REL(p)  ((int)(((p) >> 16) & 0x3FF))
#define PK_DST(p)  ((int)(((p) >> 26) & 0xFFFF))
#define PK_EID(p)  ((int)((p) >> 42))

// ---------------------------------------------------------------- CSR build
__global__ void hist_kernel(const int* __restrict__ dst, int* __restrict__ counts) {
    int t = blockIdx.x * 256 + threadIdx.x;
    if (t < N_EDGE) atomicAdd(&counts[dst[t]], 1);
}

// block partial sums: 13 blocks x 1024 threads x 4 elems
__global__ void scan_partial(const int* __restrict__ counts, int* __restrict__ blk_sum) {
    int t = threadIdx.x, b = blockIdx.x;
    int i0 = b * 4096 + t * 4;
    int s = 0;
    #pragma unroll
    for (int q = 0; q < 4; ++q) { int i = i0 + q; if (i < N_NODES) s += counts[i]; }
    #pragma unroll
    for (int off = 32; off > 0; off >>= 1) s += __shfl_down(s, off, 64);
    __shared__ int ws[16];
    if ((t & 63) == 0) ws[t >> 6] = s;
    __syncthreads();
    if (t == 0) { int tot = 0; for (int i = 0; i < 16; ++i) tot += ws[i]; blk_sum[b] = tot; }
}

__global__ void scan_small(int* __restrict__ blk_sum, int* __restrict__ row_ptr) {
    if (threadIdx.x == 0) {
        int acc = 0;
        for (int i = 0; i < SCAN_NBLK; ++i) { int v = blk_sum[i]; blk_sum[i] = acc; acc += v; }
        row_ptr[N_NODES] = acc;   // == N_EDGE
    }
}

__global__ void scan_final(const int* __restrict__ counts, const int* __restrict__ blk_sum,
                           int* __restrict__ row_ptr) {
    __shared__ int wtot[16];
    __shared__ int wpre[16];
    int b = blockIdx.x, t = threadIdx.x;
    int lane = t & 63, wid = t >> 6;
    int i0 = b * 4096 + t * 4;
    int x0 = (i0 + 0 < N_NODES) ? counts[i0 + 0] : 0;
    int x1 = (i0 + 1 < N_NODES) ? counts[i0 + 1] : 0;
    int x2 = (i0 + 2 < N_NODES) ? counts[i0 + 2] : 0;
    int x3 = (i0 + 3 < N_NODES) ? counts[i0 + 3] : 0;
    int tsum = x0 + x1 + x2 + x3;
    int v = tsum;
    #pragma unroll
    for (int off = 1; off < 64; off <<= 1) {
        int u = __shfl_up(v, off, 64);
        if (lane >= off) v += u;
    }
    if (lane == 63) wtot[wid] = v;
    __syncthreads();
    if (wid == 0) {
        int wv = (lane < 16) ? wtot[lane] : 0;
        #pragma unroll
        for (int off = 1; off < 16; off <<= 1) {
            int u = __shfl_up(wv, off, 64);
            if (lane >= off) wv += u;
        }
        if (lane < 16) wpre[lane] = wv;
    }
    __syncthreads();
    int wbase = (wid == 0) ? 0 : wpre[wid - 1];
    int ex = blk_sum[b] + wbase + (v - tsum);
    if (i0 + 0 < N_NODES) row_ptr[i0 + 0] = ex;
    if (i0 + 1 < N_NODES) row_ptr[i0 + 1] = ex + x0;
    if (i0 + 2 < N_NODES) row_ptr[i0 + 2] = ex + x0 + x1;
    if (i0 + 3 < N_NODES) row_ptr[i0 + 3] = ex + x0 + x1 + x2;
}

__global__ void init_bcursor(const int* __restrict__ row_ptr, int* __restrict__ bcursor) {
    int t = threadIdx.x;   // 64
    if (t < NBUCK) {
        int d = t * DST_PER_BUCK;
        bcursor[t] = row_ptr[d < N_NODES ? d : N_NODES];
    }
}

// ---------------------------------------------------------------- level-1: LDS-grouped bucket scatter
__global__ __launch_bounds__(1024) void bucket_scatter_l1(
        const int* __restrict__ src, const int* __restrict__ dst, const int* __restrict__ rel,
        int* __restrict__ bcursor, u64* __restrict__ staging) {
    __shared__ u64 buf[L1_EDGES];
    __shared__ unsigned char bb[L1_EDGES];
    __shared__ int hist[NBUCK], lstart[NBUCK], cur[NBUCK], delta[NBUCK];
    int t = threadIdx.x;
    int e0 = blockIdx.x * L1_EDGES;
    if (t < NBUCK) hist[t] = 0;
    __syncthreads();

    u64 myp[4]; int myb[4]; bool mv[4];
    #pragma unroll
    for (int q = 0; q < 4; ++q) {
        int e = e0 + q * 1024 + t;
        mv[q] = (e < N_EDGE);
        if (mv[q]) {
            int d = dst[e];
            int b = d / DST_PER_BUCK;
            myp[q] = ((u64)(unsigned)e << 42) | ((u64)(unsigned)d << 26)
                   | ((unsigned)rel[e] << 16) | (unsigned)src[e];
            myb[q] = b;
            atomicAdd(&hist[b], 1);
        }
    }
    __syncthreads();
    if (t < NBUCK) {       // exclusive scan of hist (wave 0, 64 lanes)
        int v = hist[t];
        int inc = v;
        #pragma unroll
        for (int off = 1; off < 64; off <<= 1) {
            int u = __shfl_up(inc, off, 64);
            if (t >= off) inc += u;
        }
        lstart[t] = inc - v;
        cur[t] = inc - v;
    }
    __syncthreads();
    #pragma unroll
    for (int q = 0; q < 4; ++q) {
        if (mv[q]) {
            int lp = atomicAdd(&cur[myb[q]], 1);
            buf[lp] = myp[q];
            bb[lp] = (unsigned char)myb[q];
        }
    }
    __syncthreads();
    if (t < NBUCK && hist[t] > 0) {
        int g = atomicAdd(&bcursor[t], hist[t]);
        delta[t] = g - lstart[t];
    }
    __syncthreads();
    int total = N_EDGE - e0; if (total > L1_EDGES) total = L1_EDGES;
    for (int i = t; i < total; i += 1024) {
        staging[(size_t)(delta[bb[i]] + i)] = buf[i];
    }
}

// ---------------------------------------------------------------- level-2: exact placement, one block per bucket
__global__ __launch_bounds__(1024) void bucket_scatter_l2(
        const u64* __restrict__ staging, const int* __restrict__ row_ptr,
        u64* __restrict__ sorted_pack) {
    __shared__ int cur[DST_PER_BUCK];
    int b = blockIdx.x, t = threadIdx.x;
    int d0 = b * DST_PER_BUCK;
    int d1 = d0 + DST_PER_BUCK; if (d1 > N_NODES) d1 = N_NODES;
    int nd = d1 - d0;
    for (int i = t; i < nd; i += 1024) cur[i] = row_ptr[d0 + i];
    __syncthreads();
    int rbeg = row_ptr[d0], rend = row_ptr[d1];
    for (int j = rbeg + t; j < rend; j += 1024) {
        u64 p = staging[j];
        int d = PK_DST(p);
        int pos = atomicAdd(&cur[d - d0], 1);
        sorted_pack[pos] = p;
    }
}

// ---------------------------------------------------------------- dense: dual GEMM + score epilogue
__global__ __launch_bounds__(256) void gemm_dual(
        const float* __restrict__ A, const float* __restrict__ W1, const float* __restrict__ W2,
        const float* __restrict__ a_vec,
        float* __restrict__ C1, float* __restrict__ C2,
        float* __restrict__ s_src, float* __restrict__ s_dst, int n) {
    __shared__ float W1s[64][64];   // [k][c]
    __shared__ float W2s[64][64];
    __shared__ float As[32][64];
    __shared__ float a_sh[128];
    int t = threadIdx.x;      // 256
    const float4* W1v = (const float4*)W1;
    const float4* W2v = (const float4*)W2;
    for (int i = t; i < 1024; i += 256) {
        ((float4*)W1s)[i] = W1v[i];
        ((float4*)W2s)[i] = W2v[i];
    }
    if (t < 128) a_sh[t] = a_vec[t];   // a[0][h][d] then a[1][h][d]
    int row0 = blockIdx.x * 32;
    const float4* Av = (const float4*)A;
    for (int i = t; i < 512; i += 256) {       // 32 rows * 16 float4
        int gr = row0 + (i >> 4);
        ((float4*)As)[i] = (gr < n) ? Av[(size_t)row0 * 16 + i] : make_float4(0.f, 0.f, 0.f, 0.f);
    }
    __syncthreads();
    int cq = (t & 15) * 4;     // column quad base
    int rs = t >> 4;           // row slot: rows rs and rs+16
    float4 a1a = make_float4(0.f,0.f,0.f,0.f), a1b = a1a, a2a = a1a, a2b = a1a;
    #pragma unroll 4
    for (int k = 0; k < 64; ++k) {
        float va = As[rs][k];
        float vb = As[rs + 16][k];
        float4 w1 = *(const float4*)&W1s[k][cq];
        float4 w2 = *(const float4*)&W2s[k][cq];
        a1a.x += va * w1.x; a1a.y += va * w1.y; a1a.z += va * w1.z; a1a.w += va * w1.w;
        a2a.x += va * w2.x; a2a.y += va * w2.y; a2a.z += va * w2.z; a2a.w += va * w2.w;
        a1b.x += vb * w1.x; a1b.y += vb * w1.y; a1b.z += vb * w1.z; a1b.w += vb * w1.w;
        a2b.x += vb * w2.x; a2b.y += vb * w2.y; a2b.z += vb * w2.z; a2b.w += vb * w2.w;
    }
    int gra = row0 + rs, grb = row0 + rs + 16;
    if (gra < n) {
        *(float4*)&C1[(size_t)gra * 64 + cq] = a1a;
        *(float4*)&C2[(size_t)gra * 64 + cq] = a2a;
    }
    if (grb < n) {
        *(float4*)&C1[(size_t)grb * 64 + cq] = a1b;
        *(float4*)&C2[(size_t)grb * 64 + cq] = a2b;
    }
    __syncthreads();                       // all As reads done
    *(float4*)&As[rs][cq]      = a1a;      // park C1 tile for the score epilogue
    *(float4*)&As[rs + 16][cq] = a1b;
    __syncthreads();
    if (t < 128) {                         // (node-in-tile, head) dots
        int nl = t >> 2, h = t & 3;
        int gr = row0 + nl;
        if (gr < n) {
            float ss = 0.f, sd = 0.f;
            #pragma unroll
            for (int d = 0; d < 16; ++d) {
                float v = As[nl][h * 16 + d];
                ss += v * a_sh[h * 16 + d];
                sd += v * a_sh[64 + h * 16 + d];
            }
            s_src[gr * 4 + h] = ss;
            s_dst[gr * 4 + h] = sd;
        }
    }
}

// s_rel[r,h] = dot((rel_emb @ W_rel)[r, h*16:...], a2[h,:])
__global__ void rel_scores(const float* __restrict__ rel_emb, const float* __restrict__ Wr,
                           const float* __restrict__ a2, float* __restrict__ s_rel) {
    __shared__ float proj[64];
    int r = blockIdx.x, c = threadIdx.x;   // 64 threads
    float acc = 0.f;
    #pragma unroll
    for (int k = 0; k < 64; ++k) acc += rel_emb[(size_t)r * 64 + k] * Wr[k * 64 + c];
    proj[c] = acc;
    __syncthreads();
    if (c < HEADS) {
        float s = 0.f;
        #pragma unroll
        for (int d = 0; d < 16; ++d) s += proj[c * 16 + d] * a2[c * 16 + d];
        s_rel[r * HEADS + c] = s;
    }
}

// ---------------------------------------------------------------- edge scores (head-major planes)
__global__ void edge_scores(const u64* __restrict__ pack, const float* __restrict__ s_src,
                            const float* __restrict__ s_rel, float* __restrict__ sc) {
    int j = blockIdx.x * 256 + threadIdx.x;
    if (j >= N_EDGE) return;
    u64 p = pack[j];
    int src = PK_SRC(p);
    int rel = PK_REL(p);
    float4 a = *(const float4*)(s_src + (size_t)src * 4);
    float4 b = *(const float4*)(s_rel + (size_t)rel * 4);
    sc[0 * N_EDGE + j] = a.x + b.x;
    sc[1 * N_EDGE + j] = a.y + b.y;
    sc[2 * N_EDGE + j] = a.z + b.z;
    sc[3 * N_EDGE + j] = a.w + b.w;
}

// ---------------------------------------------------------------- top-k + softmax (streaming)
// selects on RAW sc (lrelu(x+sdst) strictly monotone -> same order & ties);
// transform applied only to the <=10 survivors.
__global__ void topk_kernel(const int* __restrict__ row_ptr, const u64* __restrict__ pack,
                            const float* __restrict__ sc_all, const float* __restrict__ s_dst,
                            int* __restrict__ kept_src, float* __restrict__ kept_w,
                            int* __restrict__ kept_cnt) {
    int t = blockIdx.x * 256 + threadIdx.x;
    if (t >= N_NODES * HEADS) return;
    int d = t >> 2, h = t & 3;
    int beg = row_ptr[d], end = row_ptr[d + 1];
    const float* sc = sc_all + (size_t)h * N_EDGE;

    float topS[TOPK]; int topI[TOPK]; int topN[TOPK];
    #pragma unroll
    for (int i = 0; i < TOPK; ++i) { topS[i] = -3.4e38f; topI[i] = 0x7fffffff; topN[i] = 0; }

    auto ins = [&](float s, int j) {
        if (s < topS[TOPK - 1]) return;
        u64 p = pack[j];
        int id = PK_EID(p);
        int sn = PK_SRC(p);
        if (s == topS[TOPK - 1] && id > topI[TOPK - 1]) return;
        #pragma unroll
        for (int i = 0; i < TOPK; ++i) {      // rank by (score desc, edge id asc)
            bool better = (s > topS[i]) || (s == topS[i] && id < topI[i]);
            if (better) {
                float ts = topS[i]; int ti = topI[i]; int tn = topN[i];
                topS[i] = s; topI[i] = id; topN[i] = sn;
                s = ts; id = ti; sn = tn;
            }
        }
    };

    int j = beg;
    for (; j + 4 <= end; j += 4) {
        float s0 = sc[j + 0];
        float s1 = sc[j + 1];
        float s2 = sc[j + 2];
        float s3 = sc[j + 3];
        float mx = fmaxf(fmaxf(s0, s1), fmaxf(s2, s3));
        if (mx < topS[TOPK - 1]) continue;    // whole batch below slot 9
        ins(s0, j + 0); ins(s1, j + 1); ins(s2, j + 2); ins(s3, j + 3);
    }
    for (; j < end; ++j) ins(sc[j], j);

    int deg = end - beg;
    int cnt = deg < TOPK ? deg : TOPK;
    float sdst = s_dst[t];
    float tm = topS[0] + sdst;
    tm = tm > 0.f ? tm : SLOPE * tm;          // transformed max (monotone)
    float w[TOPK]; float den = 0.f;
    #pragma unroll
    for (int i = 0; i < TOPK; ++i) {
        float ti = topS[i] + sdst;
        ti = ti > 0.f ? ti : SLOPE * ti;
        float e = (i < cnt) ? expf(ti - tm) : 0.f;
        w[i] = e; den += e;
    }
    float inv = 1.f / (den + 1e-16f);
    #pragma unroll
    for (int i = 0; i < TOPK; ++i) {
        kept_w[(size_t)t * TOPK + i]   = (i < cnt) ? w[i] * inv : 0.f;
        kept_src[(size_t)t * TOPK + i] = topN[i];
    }
    kept_cnt[t] = cnt;
}

// ---------------------------------------------------------------- diffusion hop (float4)
// 256 threads = 16 nodes x 16 float4-lanes
template<bool FINAL>
__global__ void hop_kernel(const float4* __restrict__ hc_in, const float4* __restrict__ feat0,
                           const int* __restrict__ kept_src, const float* __restrict__ kept_w,
                           const int* __restrict__ kept_cnt,
                           const float4* __restrict__ res, float4* __restrict__ out) {
    __shared__ int   ls[16 * HEADS * TOPK];
    __shared__ float lw[16 * HEADS * TOPK];
    __shared__ int   lc[16 * HEADS];
    int tb = threadIdx.x;            // 256
    int nb = blockIdx.x * 16;        // first node
    for (int i = tb; i < 16 * HEADS * TOPK; i += 256) {
        int idx = nb * HEADS * TOPK + i;
        ls[i] = kept_src[idx];
        lw[i] = kept_w[idx];
    }
    if (tb < 16 * HEADS) lc[tb] = kept_cnt[nb * HEADS + tb];
    __syncthreads();
    int nl = tb >> 4;                // node in block
    int c4 = tb & 15;                // float4 column
    int h  = c4 >> 2;
    int lbase = nl * HEADS * TOPK + h * TOPK;
    int cnt = lc[nl * HEADS + h];
    float4 acc = make_float4(0.f, 0.f, 0.f, 0.f);
    for (int k = 0; k < cnt; ++k) {
        float w = lw[lbase + k];
        int s = ls[lbase + k];
        float4 v = hc_in[(size_t)s * 16 + c4];
        acc.x += w * v.x; acc.y += w * v.y; acc.z += w * v.z; acc.w += w * v.w;
    }
    size_t o = (size_t)nb * 16 + tb;
    float4 f = feat0[o];
    float4 r;
    r.x = (1.f - ALPHA) * acc.x + ALPHA * f.x;
    r.y = (1.f - ALPHA) * acc.y + ALPHA * f.y;
    r.z = (1.f - ALPHA) * acc.z + ALPHA * f.z;
    r.w = (1.f - ALPHA) * acc.w + ALPHA * f.w;
    if (FINAL) {
        float4 rs = res[o];
        float x;
        x = r.x + rs.x; r.x = x > 0.f ? x : (expf(x) - 1.f);
        x = r.y + rs.y; r.y = x > 0.f ? x : (expf(x) - 1.f);
        x = r.z + rs.z; r.z = x > 0.f ? x : (expf(x) - 1.f);
        x = r.w + rs.w; r.w = x > 0.f ? x : (expf(x) - 1.f);
    }
    out[o] = r;
}

// ---------------------------------------------------------------- rel output
__global__ void relout_kernel(const float* __restrict__ rel_emb, const float* __restrict__ Wf,
                              float* __restrict__ out) {
    int r = blockIdx.x, c = threadIdx.x;  // 500 x 64
    float acc = 0.f;
    #pragma unroll
    for (int k = 0; k < 64; ++k) acc += rel_emb[(size_t)r * 64 + k] * Wf[k * 64 + c];
    out[(size_t)r * 64 + c] = acc;
}

// ---------------------------------------------------------------- launch
extern "C" void kernel_launch(void* const* d_in, const int* in_sizes, int n_in,
                              void* d_out, int out_size, void* d_ws, size_t ws_size,
                              hipStream_t stream) {
    (void)in_sizes; (void)n_in; (void)out_size; (void)ws_size;
    const float* ent_emb  = (const float*)d_in[0];
    const float* rel_emb  = (const float*)d_in[1];
    const int*   edge_src = (const int*)d_in[2];
    const int*   edge_dst = (const int*)d_in[3];
    const int*   edge_rel = (const int*)d_in[4];
    const float* W_ent    = (const float*)d_in[5];
    const float* W_rel    = (const float*)d_in[6];
    const float* attn_a   = (const float*)d_in[7];
    const float* res_W    = (const float*)d_in[8];
    const float* fc_rel_w = (const float*)d_in[9];

    char* wp = (char*)d_ws;
    auto alloc = [&](size_t bytes) -> void* {
        void* p = (void*)wp;
        wp += (bytes + 255) & ~(size_t)255;
        return p;
    };
    int*   counts     = (int*)alloc((size_t)N_NODES * 4);
    int*   row_ptr    = (int*)alloc((size_t)(N_NODES + 1) * 4);
    int*   blk_sum    = (int*)alloc((size_t)SCAN_NBLK * 4);
    int*   bcursor    = (int*)alloc((size_t)NBUCK * 4);
    u64*   staging    = (u64*)alloc((size_t)N_EDGE * 8);
    u64*   sorted_pack= (u64*)alloc((size_t)N_EDGE * 8);
    float* s_src      = (float*)alloc((size_t)N_NODES * HEADS * 4);
    float* s_dst      = (float*)alloc((size_t)N_NODES * HEADS * 4);
    float* s_rel      = (float*)alloc((size_t)N_RELS * HEADS * 4);
    float* feat0      = (float*)alloc((size_t)N_NODES * HID * 4);
    float* hcA        = (float*)alloc((size_t)N_NODES * HID * 4);
    float* hcB        = (float*)alloc((size_t)N_NODES * HID * 4);   // aliased as sc planes
    float* res        = (float*)alloc((size_t)N_NODES * HID * 4);
    int*   kept_src   = (int*)alloc((size_t)N_NODES * HEADS * TOPK * 4);
    float* kept_w     = (float*)alloc((size_t)N_NODES * HEADS * TOPK * 4);
    int*   kept_cnt   = (int*)alloc((size_t)N_NODES * HEADS * 4);
    float* sc_planes  = hcB;   // 4 * E * 4B == N*HID*4B == 12.8 MB, disjoint lifetime

    // ---- CSR by destination (edges are layer-invariant: build once) ----
    hipMemsetAsync(counts, 0, (size_t)N_NODES * 4, stream);
    hist_kernel<<<N_EDGE / 256, 256, 0, stream>>>(edge_dst, counts);
    scan_partial<<<SCAN_NBLK, 1024, 0, stream>>>(counts, blk_sum);
    scan_small<<<1, 64, 0, stream>>>(blk_sum, row_ptr);
    scan_final<<<SCAN_NBLK, 1024, 0, stream>>>(counts, blk_sum, row_ptr);
    init_bcursor<<<1, 64, 0, stream>>>(row_ptr, bcursor);
    bucket_scatter_l1<<<L1_NBLK, 1024, 0, stream>>>(edge_src, edge_dst, edge_rel,
                                                    bcursor, staging);
    bucket_scatter_l2<<<NBUCK, 1024, 0, stream>>>(staging, row_ptr, sorted_pack);

    float* out_h = (float*)d_out;     // node rows; layer-1 output also lives here
    const float* h = ent_emb;
    const int nb_gemm = (N_NODES + 31) / 32;
    const int nb_nh   = (N_NODES * HEADS + 255) / 256;
    const int nb_edge = (N_EDGE + 255) / 256;
    const int nb_hop  = N_NODES / 16;   // 3125, exact

    for (int l = 0; l < LAYERS; ++l) {
        const float* We = W_ent + (size_t)l * HID * HID;
        const float* Wr = W_rel + (size_t)l * HID * HID;
        const float* a  = attn_a + (size_t)l * 3 * HEADS * DH;
        const float* rW = res_W + (size_t)l * HID * HID;

        gemm_dual<<<nb_gemm, 256, 0, stream>>>(h, We, rW, a, feat0, res, s_src, s_dst, N_NODES);
        rel_scores<<<N_RELS, 64, 0, stream>>>(rel_emb, Wr, a + 2 * HEADS * DH, s_rel);
        edge_scores<<<nb_edge, 256, 0, stream>>>(sorted_pack, s_src, s_rel, sc_planes);
        topk_kernel<<<nb_nh, 256, 0, stream>>>(row_ptr, sorted_pack, sc_planes,
                                               s_dst, kept_src, kept_w, kept_cnt);
        hop_kernel<false><<<nb_hop, 256, 0, stream>>>((const float4*)feat0, (const float4*)feat0,
                                                      kept_src, kept_w, kept_cnt, nullptr, (float4*)hcA);
        hop_kernel<false><<<nb_hop, 256, 0, stream>>>((const float4*)hcA, (const float4*)feat0,
                                                      kept_src, kept_w, kept_cnt, nullptr, (float4*)hcB);
        hop_kernel<true><<<nb_hop, 256, 0, stream>>>((const float4*)hcB, (const float4*)feat0,
                                                     kept_src, kept_w, kept_cnt, (const float4*)res,
                                                     (float4*)out_h);
        h = out_h;
    }
    relout_kernel<<<N_RELS, 64, 0, stream>>>(rel_emb, fc_rel_w, (float*)d_out + (size_t)N_NODES * HID);
}